// Round 2
// 920.770 us; speedup vs baseline: 1.0149x; 1.0149x over previous
//
#include <hip/hip_runtime.h>

#define CC 256          // channels
#define GG 1024         // graphs
#define RR 16           // bottleneck dim (C/R)
#define ROWS_PER_BLOCK 256

// native clang vector type — required by __builtin_nontemporal_load/store
// (HIP_vector_type float4 is a struct and is rejected).
typedef float f32x4 __attribute__((ext_vector_type(4)));

// ---------------- Kernel 1: segment sum + counts (sorted batch_idx) --------
// Block = 256 threads = 4 waves. Wave w handles rows base+w, base+w+4, ...
// Lane l holds channels [4l, 4l+4) as a float4 register accumulator.
// Flush to global atomics only when the graph id changes (sorted input) or
// at the end of the chunk -> ~16K atomic flushes instead of 128M.
// NOTE: regular (caching) loads on purpose — the tail ~256MB of x stays
// L3-resident and is re-consumed first by the reversed apply_kernel.
__global__ void seg_sum_kernel(const float* __restrict__ x,
                               const int* __restrict__ batch_idx,
                               float* __restrict__ seg,
                               float* __restrict__ cnt,
                               int n) {
    const int wave = threadIdx.x >> 6;
    const int lane = threadIdx.x & 63;
    const int base = blockIdx.x * ROWS_PER_BLOCK;
    const int rend = min(base + ROWS_PER_BLOCK, n);

    float4 acc = make_float4(0.f, 0.f, 0.f, 0.f);
    int cur_g = -1;
    int cl = 0;

    for (int row = base + wave; row < rend; row += 4) {
        const int g = batch_idx[row];          // wave-uniform (all lanes same row)
        if (g != cur_g) {                      // wave-uniform branch
            if (cur_g >= 0) {
                float* p = seg + (size_t)cur_g * CC + lane * 4;
                atomicAdd(p + 0, acc.x);
                atomicAdd(p + 1, acc.y);
                atomicAdd(p + 2, acc.z);
                atomicAdd(p + 3, acc.w);
                if (lane == 0) atomicAdd(cnt + cur_g, (float)cl);
            }
            cur_g = g;
            acc = make_float4(0.f, 0.f, 0.f, 0.f);
            cl = 0;
        }
        const float4 v =
            *reinterpret_cast<const float4*>(x + (size_t)row * CC + lane * 4);
        acc.x += v.x; acc.y += v.y; acc.z += v.z; acc.w += v.w;
        ++cl;
    }
    if (cur_g >= 0) {
        float* p = seg + (size_t)cur_g * CC + lane * 4;
        atomicAdd(p + 0, acc.x);
        atomicAdd(p + 1, acc.y);
        atomicAdd(p + 2, acc.z);
        atomicAdd(p + 3, acc.w);
        if (lane == 0) atomicAdd(cnt + cur_g, (float)cl);
    }
}

// ---------------- Kernel 2: mean + Linear(256->16) + PReLU + Linear(16->256)
//                  + sigmoid. One block (256 thr) per graph. Tiny. ----------
__global__ void mlp_kernel(const float* __restrict__ seg,
                           const float* __restrict__ cnt,
                           const float* __restrict__ W1,
                           const float* __restrict__ prelu_a,
                           const float* __restrict__ W2,
                           float* __restrict__ score) {
    __shared__ float xm[CC];
    __shared__ float h[RR];
    const int g = blockIdx.x;
    const int t = threadIdx.x;

    const float c   = cnt[g];
    const float inv = 1.0f / fmaxf(c, 1.0f);
    xm[t] = seg[(size_t)g * CC + t] * inv;
    __syncthreads();

    if (t < RR) {
        const float a = *prelu_a;
        float acc = 0.f;
        const float* w = W1 + t * CC;      // W1[r, c] row-major, 'gc,rc->gr'
        #pragma unroll 8
        for (int cc2 = 0; cc2 < CC; ++cc2) acc += xm[cc2] * w[cc2];
        h[t] = (acc >= 0.f) ? acc : a * acc;   // PReLU, scalar a
    }
    __syncthreads();

    float acc2 = 0.f;
    const float* w2 = W2 + t * RR;         // W2[c, r] row-major, 'gr,cr->gc'
    #pragma unroll
    for (int r = 0; r < RR; ++r) acc2 += h[r] * w2[r];
    score[(size_t)g * CC + t] = 1.0f / (1.0f + __expf(-acc2));
}

// ---------------- Kernel 3: out = x * score[batch_idx], float4 lanes -------
// Lanes of one wave cover exactly one row (64 * float4 = 256 ch): batch_idx
// load is wave-uniform, score row read is a coalesced 1 KiB L2 hit.
//
// L3-reuse scheme: seg_sum streamed x in ASCENDING row order, so the tail
// ~256MB of x is L3 (Infinity Cache)-resident when apply starts. We reverse
// the block->chunk mapping so the earliest blocks consume the hot tail
// first, and use non-temporal loads/stores so the streaming re-read of the
// cold head and the 512MB of out writes don't evict not-yet-consumed x
// lines. Within a block the access pattern is unchanged (fully coalesced).
__global__ void apply_kernel(const f32x4* __restrict__ x4,
                             const int* __restrict__ batch_idx,
                             const float4* __restrict__ score4,
                             f32x4* __restrict__ out4,
                             long total) {
    const long i = (long)(gridDim.x - 1 - blockIdx.x) * blockDim.x + threadIdx.x;
    if (i >= total) return;
    const int row = (int)(i >> 6);
    const int c4  = (int)(i & 63);
    const int g   = batch_idx[row];
    const f32x4 v = __builtin_nontemporal_load(&x4[i]);
    const float4 s = score4[(size_t)g * 64 + c4];   // cached: 1MB, L2-resident
    f32x4 o;
    o.x = v.x * s.x; o.y = v.y * s.y; o.z = v.z * s.z; o.w = v.w * s.w;
    __builtin_nontemporal_store(o, &out4[i]);
}

extern "C" void kernel_launch(void* const* d_in, const int* in_sizes, int n_in,
                              void* d_out, int out_size, void* d_ws, size_t ws_size,
                              hipStream_t stream) {
    // inputs: 0=x [N*C f32], 1=batch_idx [N i32], 2=num_graphs (i32 scalar),
    //         3=W1 [16*256 f32], 4=prelu_a (f32 scalar), 5=W2 [256*16 f32]
    const float* x    = (const float*)d_in[0];
    const int*   bidx = (const int*)d_in[1];
    const float* W1   = (const float*)d_in[3];
    const float* pa   = (const float*)d_in[4];
    const float* W2   = (const float*)d_in[5];
    float*       out  = (float*)d_out;

    const int n = in_sizes[1];                 // N = 500000

    float* seg   = (float*)d_ws;               // [G, C]   = 1 MB
    float* cnt   = seg + (size_t)GG * CC;      // [G]      = 4 KB
    float* score = cnt + GG;                   // [G, C]   = 1 MB

    // ws is poisoned 0xAA before every launch: zero the accumulators.
    (void)hipMemsetAsync(d_ws, 0, ((size_t)GG * CC + GG) * sizeof(float), stream);

    const int nb1 = (n + ROWS_PER_BLOCK - 1) / ROWS_PER_BLOCK;
    seg_sum_kernel<<<nb1, 256, 0, stream>>>(x, bidx, seg, cnt, n);

    mlp_kernel<<<GG, CC, 0, stream>>>(seg, cnt, W1, pa, W2, score);

    const long total = (long)n * (CC / 4);
    const int nb3 = (int)((total + 255) / 256);
    apply_kernel<<<nb3, 256, 0, stream>>>((const f32x4*)x, bidx,
                                          (const float4*)score, (f32x4*)out,
                                          total);
}

// Round 3
// 878.100 us; speedup vs baseline: 1.0642x; 1.0486x over previous
//
#include <hip/hip_runtime.h>

#define CC 256          // channels
#define GG 1024         // graphs
#define RR 16           // bottleneck dim (C/R)
#define NB 256          // fused-kernel grid: 1 block/CU -> L3-bounded reuse set
#define NT_THREADS 1024 // 16 waves/block

typedef float f32x4 __attribute__((ext_vector_type(4)));

// ---------------- Kernel 0: graph row-range boundaries ---------------------
// batch_idx is sorted. bounds[g] = lower_bound(batch_idx, g), bounds[GG] = n.
// 1025 parallel binary searches, ~19 L2 loads each. ~2 us.
__global__ void bounds_kernel(const int* __restrict__ bidx,
                              int* __restrict__ bounds, int n) {
    const int g = blockIdx.x * blockDim.x + threadIdx.x;
    if (g > GG) return;
    int lo = 0, hi = n;
    while (lo < hi) {
        const int mid = (lo + hi) >> 1;
        if (bidx[mid] < g) lo = mid + 1; else hi = mid;
    }
    bounds[g] = lo;
}

// ---------------- Kernel 1 (fused): per-graph mean -> MLP -> scale ---------
// One block processes whole graphs (grid-stride over g). Per graph:
//   pass 1: 16 waves stream the graph's contiguous rows; lane l holds
//           channels [4l,4l+4) as an f32x4 accumulator. LDS tree-reduce
//           across waves -> mean[256].
//   MLP:    W1 (256->16) parallelized 16 outputs x 16-lane partials with
//           shfl_xor reduce; PReLU; W2 (16->256) one output/thread; sigmoid.
//   pass 2: re-read the SAME rows (L3-resident: 256 blocks x ~488KB = 122MB
//           < 256MB Infinity Cache) and write out = x * score with
//           non-temporal stores (out is never re-read; don't evict x).
__global__ __launch_bounds__(NT_THREADS) void fused_kernel(
        const float* __restrict__ x,
        const int* __restrict__ bounds,
        const float* __restrict__ W1,
        const float* __restrict__ prelu_a,
        const float* __restrict__ W2,
        float* __restrict__ out) {
    __shared__ f32x4 part[16][64];   // per-wave partial sums (16 KB)
    __shared__ float xm[CC];         // graph mean
    __shared__ float h[RR];          // bottleneck activations
    __shared__ float score[CC];      // sigmoid gate

    const int t    = threadIdx.x;
    const int w    = t >> 6;         // wave 0..15
    const int lane = t & 63;         // channel quad

    for (int g = blockIdx.x; g < GG; g += gridDim.x) {
        const int start = bounds[g];
        const int end   = bounds[g + 1];
        const int rows  = end - start;
        if (rows == 0) continue;     // block-uniform: no divergent sync

        // ---- pass 1: segment sum ----
        f32x4 acc = {0.f, 0.f, 0.f, 0.f};
        #pragma unroll 2
        for (int r = start + w; r < end; r += 16) {
            const f32x4 v = *reinterpret_cast<const f32x4*>(
                x + (size_t)r * CC + 4 * lane);
            acc += v;
        }
        part[w][lane] = acc;
        __syncthreads();
        if (w < 8) { part[w][lane] += part[w + 8][lane]; } __syncthreads();
        if (w < 4) { part[w][lane] += part[w + 4][lane]; } __syncthreads();
        if (w < 2) { part[w][lane] += part[w + 2][lane]; } __syncthreads();
        if (w == 0) {
            const float inv = 1.0f / (float)rows;
            f32x4 s = part[0][lane] + part[1][lane];
            s *= inv;
            reinterpret_cast<f32x4*>(xm)[lane] = s;
        }
        __syncthreads();

        // ---- MLP stage 1: h = PReLU(W1 @ mean), 16 outputs ----
        // threads 0..255: output r = t>>4, 16-lane strided partial dot.
        if (t < 256) {
            const int r  = t >> 4;
            const int sl = t & 15;
            const float* wrow = W1 + r * CC;
            float p = 0.f;
            #pragma unroll
            for (int c = sl; c < CC; c += 16) p += xm[c] * wrow[c];
            p += __shfl_xor(p, 1);
            p += __shfl_xor(p, 2);
            p += __shfl_xor(p, 4);
            p += __shfl_xor(p, 8);
            if (sl == 0) {
                const float a = *prelu_a;
                h[r] = (p >= 0.f) ? p : a * p;
            }
        }
        __syncthreads();

        // ---- MLP stage 2: score = sigmoid(W2 @ h), 256 outputs ----
        if (t < 256) {
            const float* w2 = W2 + t * RR;
            float acc2 = 0.f;
            #pragma unroll
            for (int r = 0; r < RR; ++r) acc2 += h[r] * w2[r];
            score[t] = 1.0f / (1.0f + __expf(-acc2));
        }
        __syncthreads();

        // ---- pass 2: out = x * score (x rows now L3-resident) ----
        const f32x4 sv = reinterpret_cast<const f32x4*>(score)[lane];
        #pragma unroll 2
        for (int r = start + w; r < end; r += 16) {
            const f32x4 v = *reinterpret_cast<const f32x4*>(
                x + (size_t)r * CC + 4 * lane);
            const f32x4 o = v * sv;
            __builtin_nontemporal_store(
                o, reinterpret_cast<f32x4*>(out + (size_t)r * CC + 4 * lane));
        }
        __syncthreads();   // protect LDS before next graph
    }
}

extern "C" void kernel_launch(void* const* d_in, const int* in_sizes, int n_in,
                              void* d_out, int out_size, void* d_ws, size_t ws_size,
                              hipStream_t stream) {
    // inputs: 0=x [N*C f32], 1=batch_idx [N i32], 2=num_graphs (i32 scalar),
    //         3=W1 [16*256 f32], 4=prelu_a (f32 scalar), 5=W2 [256*16 f32]
    const float* x    = (const float*)d_in[0];
    const int*   bidx = (const int*)d_in[1];
    const float* W1   = (const float*)d_in[3];
    const float* pa   = (const float*)d_in[4];
    const float* W2   = (const float*)d_in[5];
    float*       out  = (float*)d_out;

    const int n = in_sizes[1];                 // N = 500000

    int* bounds = (int*)d_ws;                  // [GG+1] — fully overwritten

    bounds_kernel<<<(GG + 1 + 255) / 256, 256, 0, stream>>>(bidx, bounds, n);

    fused_kernel<<<NB, NT_THREADS, 0, stream>>>(x, bounds, W1, pa, W2, out);
}